// Round 10
// baseline (324.123 us; speedup 1.0000x reference)
//
#include <hip/hip_runtime.h>
#include <hip/hip_bf16.h>
#include <stdint.h>

#define B_   2
#define T_   2048
#define H_   2048
#define NH_  16
#define NKV_ 4
#define HD_  128
#define M_   (B_*T_)
#define SCALE_ 0.08838834764831845f

typedef __hip_bfloat16 bf16;
typedef __attribute__((ext_vector_type(8))) short bh8;
typedef __attribute__((ext_vector_type(4))) float f32x4;
typedef __attribute__((ext_vector_type(4))) unsigned short us4;

__device__ __forceinline__ void gload16(const bf16* g, bf16* l) {
  __builtin_amdgcn_global_load_lds(
      (const __attribute__((address_space(1))) void*)g,
      (__attribute__((address_space(3))) void*)l, 16, 0, 0);
}

__device__ __forceinline__ void cstore(bf16* p, float v)  { *p = __float2bfloat16(v); }
__device__ __forceinline__ void cstore(float* p, float v) { *p = v; }

// fp32 -> bf16 elementwise (n multiple of 8)
__global__ __launch_bounds__(256) void cvt32to16(const float* __restrict__ src,
                                                 bf16* __restrict__ dst, int n)
{
  const int stride = gridDim.x * 256 * 8;
  for (int i = (blockIdx.x * 256 + threadIdx.x) * 8; i < n; i += stride) {
    const float4 a = *(const float4*)(src + i);
    const float4 b = *(const float4*)(src + i + 4);
    bf16 o[8];
    o[0]=__float2bfloat16(a.x); o[1]=__float2bfloat16(a.y);
    o[2]=__float2bfloat16(a.z); o[3]=__float2bfloat16(a.w);
    o[4]=__float2bfloat16(b.x); o[5]=__float2bfloat16(b.y);
    o[6]=__float2bfloat16(b.z); o[7]=__float2bfloat16(b.w);
    *(bh8*)(dst + i) = *(const bh8*)o;
  }
}

// C[m][n] = sum_k A[m][k] * Bmat[n][k];  A:[M][K] row-major, Bmat:[N][K] row-major.
template<typename OutT>
__global__ __launch_bounds__(256) void gemm_bt(
    const bf16* __restrict__ A,
    const bf16* __restrict__ B0, const bf16* __restrict__ B1,
    OutT* __restrict__ C0, OutT* __restrict__ C1,
    int N, int K)
{
  const bf16* Bm = (blockIdx.z == 0) ? B0 : B1;
  OutT* Cm       = (blockIdx.z == 0) ? C0 : C1;
  const int n0 = blockIdx.x * 128;
  const int m0 = blockIdx.y * 128;
  const int tid  = threadIdx.x;
  const int lane = tid & 63;
  const int w    = tid >> 6;
  const int wr   = w >> 1, wc = w & 1;
  const int l15  = lane & 15;
  const int lk   = (lane >> 4) * 8;
  const int srow = lane >> 3;
  const int scol = (lane & 7) * 8;

  __shared__ bf16 As[128*64];
  __shared__ bf16 Bs[128*64];

  f32x4 acc[4][4] = {};

  for (int k0 = 0; k0 < K; k0 += 64) {
    #pragma unroll
    for (int i = 0; i < 4; ++i) {
      const int chunk = w*4 + i;
      const int row   = chunk*8 + srow;
      gload16(A  + (size_t)(m0+row)*K + k0 + scol, &As[chunk*512 + lane*8]);
      gload16(Bm + (size_t)(n0+row)*K + k0 + scol, &Bs[chunk*512 + lane*8]);
    }
    __syncthreads();
    #pragma unroll
    for (int kk = 0; kk < 2; ++kk) {
      bh8 af[4], bfr[4];
      #pragma unroll
      for (int mi=0;mi<4;mi++) af[mi]  = *(const bh8*)&As[(wr*64 + mi*16 + l15)*64 + kk*32 + lk];
      #pragma unroll
      for (int nj=0;nj<4;nj++) bfr[nj] = *(const bh8*)&Bs[(wc*64 + nj*16 + l15)*64 + kk*32 + lk];
      #pragma unroll
      for (int mi=0;mi<4;mi++)
        #pragma unroll
        for (int nj=0;nj<4;nj++)
          acc[mi][nj] = __builtin_amdgcn_mfma_f32_16x16x32_bf16(af[mi], bfr[nj], acc[mi][nj], 0,0,0);
    }
    __syncthreads();
  }

  #pragma unroll
  for (int mi=0;mi<4;mi++)
    #pragma unroll
    for (int r=0;r<4;r++) {
      const int row = m0 + wr*64 + mi*16 + (lane>>4)*4 + r;
      #pragma unroll
      for (int nj=0;nj<4;nj++) {
        const int col = n0 + wc*64 + nj*16 + l15;
        cstore(&Cm[(size_t)row*N + col], acc[mi][nj][r]);
      }
    }
}

// Per (b,t): RMSNorm(HD) + RoPE IN PLACE. Lane l owns d=l and d=l+64.
__global__ __launch_bounds__(256) void postproc(
    bf16* __restrict__ q, bf16* __restrict__ k,
    const float* __restrict__ qw, const float* __restrict__ kw)
{
  const int blk  = blockIdx.x;
  const int t    = blk & (T_-1);
  const int lane = threadIdx.x & 63;
  const int w    = threadIdx.x >> 6;

  const float inv = expf(-(float)lane * (9.210340371976184f / 64.f));
  const float ang = (float)t * inv;
  const float cw = cosf(ang), sw = sinf(ang);

  #pragma unroll
  for (int hi = 0; hi < 4; ++hi) {
    const int h = w + hi*4;
    bf16* row = q + (size_t)blk*(NH_*HD_) + h*HD_;
    float x1 = __bfloat162float(row[lane]);
    float x2 = __bfloat162float(row[lane+64]);
    float ss = x1*x1 + x2*x2;
    #pragma unroll
    for (int m = 1; m < 64; m <<= 1) ss += __shfl_xor(ss, m, 64);
    const float rs = rsqrtf(ss*(1.f/128.f) + 1e-6f);
    const float n1 = x1*rs*(1.f + qw[lane]), n2 = x2*rs*(1.f + qw[lane+64]);
    row[lane]    = __float2bfloat16(n1*cw - n2*sw);
    row[lane+64] = __float2bfloat16(n2*cw + n1*sw);
  }
  {
    bf16* row = k + (size_t)blk*(NKV_*HD_) + w*HD_;
    float x1 = __bfloat162float(row[lane]);
    float x2 = __bfloat162float(row[lane+64]);
    float ss = x1*x1 + x2*x2;
    #pragma unroll
    for (int m = 1; m < 64; m <<= 1) ss += __shfl_xor(ss, m, 64);
    const float rs = rsqrtf(ss*(1.f/128.f) + 1e-6f);
    const float n1 = x1*rs*(1.f + kw[lane]), n2 = x2*rs*(1.f + kw[lane+64]);
    row[lane]    = __float2bfloat16(n1*cw - n2*sw);
    row[lane+64] = __float2bfloat16(n2*cw + n1*sw);
  }
}

// v_raw [b*T+t][kvh*128+d]  ->  Vt [b][kvh][d][T]
__global__ __launch_bounds__(256) void vtrans(const bf16* __restrict__ vraw,
                                              bf16* __restrict__ Vt)
{
  __shared__ bf16 tile[64][65];
  const int t0 = blockIdx.x * 64;
  const int c0 = blockIdx.y * 64;
  const int b  = blockIdx.z;
  const int tx = threadIdx.x & 63;
  const int ty = threadIdx.x >> 6;
  const bf16* src = vraw + (size_t)b * T_ * (NKV_*HD_);
  bf16* dst       = Vt   + (size_t)b * (NKV_*HD_) * T_;
  #pragma unroll
  for (int i = 0; i < 16; ++i) {
    const int r = i*4 + ty;
    tile[r][tx] = src[(size_t)(t0 + r)*(NKV_*HD_) + c0 + tx];
  }
  __syncthreads();
  #pragma unroll
  for (int i = 0; i < 16; ++i) {
    const int r = i*4 + ty;
    dst[(size_t)(c0 + r)*T_ + t0 + tx] = tile[tx][r];
  }
}

// Flash attention v7: GQA-shared K/V. Block = 512 threads = 8 waves
// (4 heads x 2 q-halves), 32 q-rows/head per block -> each staged K/V tile
// feeds 128 q-rows (2x v6 intensity, half the L2 traffic). LDS 51200B ->
// 3 blocks/CU = 24 waves/CU for latency hiding. Inner loop identical to the
// verified v6 wave math. Heavy-first grid: s = 63 - bx.
__global__ __launch_bounds__(512, 6) void attn(
    const bf16* __restrict__ Q, const bf16* __restrict__ Kb,
    const bf16* __restrict__ Vt, bf16* __restrict__ att)
{
  const int s   = 63 - blockIdx.x;     // 32-row q slice, heavy-first
  const int kvh = blockIdx.y;          // 0..3
  const int b   = blockIdx.z;          // 0..1
  const int tid = threadIdx.x, lane = tid & 63, w = tid >> 6;  // w 0..7
  const int h   = kvh*4 + (w & 3);     // this wave's q head
  const int l15 = lane & 15;
  const int g   = lane >> 4;           // 0..3
  const int lr4 = g * 4;
  const int swz = l15 & 7;             // read-side swizzle selector

  const int q0w = s*32 + (w >> 2)*16;  // this wave's 16 q-rows
  const int nt  = (s >> 1) + 1;        // KV tiles of 64

  __shared__ bf16 Ks[64*128];          // [kv][d], swizzled 16B slots
  __shared__ bf16 Vs[128*64];          // [d][kv], swizzled 16B slots
  __shared__ bf16 Plds[8][16*72];      // wave-private P

  const bf16* Kglob = Kb + (size_t)b*T_*(NKV_*HD_) + kvh*HD_;
  const bf16* Vglob = Vt + (size_t)(b*NKV_ + kvh)*HD_*T_;

  bh8 aQ[4];
  #pragma unroll
  for (int kk = 0; kk < 4; ++kk)
    aQ[kk] = *(const bh8*)&Q[(size_t)(b*T_ + q0w + l15)*(NH_*HD_) + h*HD_ + kk*32 + g*8];

  f32x4 acc[8] = {};
  float mL = -1e30f, lL = 0.f;

  for (int j = 0; j < nt; ++j) {
    const int kv0 = j*64;

    // stage K tile: 1024 x 16B chunks over 512 threads (2 each)
    #pragma unroll
    for (int i = 0; i < 2; ++i) {
      const int o = i*512 + tid;
      const int r = o >> 4, sl = o & 15;
      gload16(Kglob + (size_t)(kv0 + r)*(NKV_*HD_) + ((sl ^ (r & 7)) << 3),
              &Ks[o*8]);
    }
    // stage V tile
    #pragma unroll
    for (int i = 0; i < 2; ++i) {
      const int o = i*512 + tid;
      const int d = o >> 3, sl = o & 7;
      gload16(Vglob + (size_t)d*T_ + kv0 + ((sl ^ (d & 7)) << 3),
              &Vs[o*8]);
    }
    asm volatile("s_waitcnt vmcnt(0)" ::: "memory");
    __syncthreads();

    // QK^T (swapped): S[jb] rows = kv(jb*16+lr4+r), cols = q(l15)
    f32x4 S[4] = {};
    #pragma unroll
    for (int jb = 0; jb < 4; ++jb)
      #pragma unroll
      for (int kk = 0; kk < 4; ++kk) {
        const bh8 kf = *(const bh8*)&Ks[(jb*16 + l15)*128 + (((kk*4 + g) ^ swz) << 3)];
        S[jb] = __builtin_amdgcn_mfma_f32_16x16x32_bf16(kf, aQ[kk], S[jb], 0,0,0);
      }

    // in-lane online softmax: lane owns q-row = q0w + l15 (16 scores)
    const bool diag = (j == nt - 1);
    float sv[16];
    float mx = -1e30f;
    #pragma unroll
    for (int jb = 0; jb < 4; ++jb)
      #pragma unroll
      for (int r = 0; r < 4; ++r) {
        float sc = S[jb][r] * SCALE_;
        if (diag && (kv0 + jb*16 + lr4 + r) > (q0w + l15)) sc = -1e30f;
        sv[jb*4 + r] = sc;
        mx = fmaxf(mx, sc);
      }
    mx = fmaxf(mx, __shfl_xor(mx, 16, 64));
    mx = fmaxf(mx, __shfl_xor(mx, 32, 64));
    const float mn = fmaxf(mL, mx);
    const float al = __expf(mL - mn);
    mL = mn;
    float sum = 0.f;
    #pragma unroll
    for (int i = 0; i < 16; ++i) { sv[i] = __expf(sv[i] - mn); sum += sv[i]; }
    sum += __shfl_xor(sum, 16, 64);
    sum += __shfl_xor(sum, 32, 64);
    lL = lL*al + sum;

    // P -> wave-private LDS (row q = l15, col kv)
    bf16* pl = Plds[w];
    #pragma unroll
    for (int jb = 0; jb < 4; ++jb) {
      bf16 pk[4];
      #pragma unroll
      for (int r = 0; r < 4; ++r) pk[r] = __float2bfloat16(sv[jb*4 + r]);
      *(us4*)(&pl[l15*72 + jb*16 + lr4]) = *(const us4*)pk;
    }

    // rescale acc (rows q = q0w + lr4 + r): al from lane with l15 = lr4+r
    float alr[4];
    #pragma unroll
    for (int r = 0; r < 4; ++r)
      alr[r] = __shfl(al, (lane & 48) | (lr4 + r), 64);
    #pragma unroll
    for (int jd = 0; jd < 8; ++jd)
      #pragma unroll
      for (int r = 0; r < 4; ++r) acc[jd][r] *= alr[r];

    // wave-local ds_write -> ds_read ordering (rule 18)
    asm volatile("s_waitcnt lgkmcnt(0)" ::: "memory");
    __builtin_amdgcn_sched_barrier(0);

    const bh8 pa0 = *(const bh8*)&pl[l15*72 + g*8];
    const bh8 pa1 = *(const bh8*)&pl[l15*72 + 32 + g*8];
    #pragma unroll
    for (int jd = 0; jd < 8; ++jd) {
      const bh8 vf0 = *(const bh8*)&Vs[(jd*16 + l15)*64 + (((g    ) ^ swz) << 3)];
      const bh8 vf1 = *(const bh8*)&Vs[(jd*16 + l15)*64 + (((4 + g) ^ swz) << 3)];
      acc[jd] = __builtin_amdgcn_mfma_f32_16x16x32_bf16(pa0, vf0, acc[jd], 0,0,0);
      acc[jd] = __builtin_amdgcn_mfma_f32_16x16x32_bf16(pa1, vf1, acc[jd], 0,0,0);
    }
    __syncthreads();   // all waves done with Ks/Vs before next staging
  }

  // epilogue: bring 1/l into acc row-space and store
  float lar[4];
  #pragma unroll
  for (int r = 0; r < 4; ++r)
    lar[r] = __shfl(lL, (lane & 48) | (lr4 + r), 64);
  #pragma unroll
  for (int r = 0; r < 4; ++r) {
    const float inv = 1.f / lar[r];
    const int row = q0w + lr4 + r;
    bf16* orow = att + ((size_t)(b*T_ + row))*(NH_*HD_) + h*HD_;
    #pragma unroll
    for (int jd = 0; jd < 8; ++jd)
      orow[jd*16 + l15] = __float2bfloat16(acc[jd][r] * inv);
  }
}

extern "C" void kernel_launch(void* const* d_in, const int* in_sizes, int n_in,
                              void* d_out, int out_size, void* d_ws, size_t ws_size,
                              hipStream_t stream) {
  const float* x  = (const float*)d_in[0];
  const float* Wq = (const float*)d_in[1];
  const float* Wk = (const float*)d_in[2];
  const float* Wv = (const float*)d_in[3];
  const float* Wo = (const float*)d_in[4];
  const float* qw = (const float*)d_in[5];
  const float* kw = (const float*)d_in[6];
  float* out = (float*)d_out;

  char* ws = (char*)d_ws;
  bf16* xb   = (bf16*)(ws);                  // 16MB  (-> att later)
  bf16* Wqb  = (bf16*)(ws + (16u<<20));      // 8MB
  bf16* Wkb  = (bf16*)(ws + (24u<<20));      // 2MB
  bf16* Wvb  = (bf16*)(ws + (26u<<20));      // 2MB
  bf16* Wob  = (bf16*)(ws + (28u<<20));      // 8MB
  bf16* kbuf = (bf16*)(ws + (36u<<20));      // 4MB
  bf16* vraw = (bf16*)(ws + (40u<<20));      // 4MB
  bf16* Vt   = (bf16*)(ws + (44u<<20));      // 4MB
  bf16* att  = xb;
  bf16* qbuf = (bf16*)d_out;                 // Q scratch in d_out

  cvt32to16<<<dim3(2048), 256, 0, stream>>>(x,  xb,  M_*H_);
  cvt32to16<<<dim3(1024), 256, 0, stream>>>(Wq, Wqb, NH_*HD_*H_);
  cvt32to16<<<dim3(256),  256, 0, stream>>>(Wk, Wkb, NKV_*HD_*H_);
  cvt32to16<<<dim3(256),  256, 0, stream>>>(Wv, Wvb, NKV_*HD_*H_);
  cvt32to16<<<dim3(1024), 256, 0, stream>>>(Wo, Wob, H_*NH_*HD_);

  gemm_bt<bf16><<<dim3(16,32,1), 256, 0, stream>>>(xb, Wqb, Wqb, qbuf, qbuf, NH_*HD_, H_);
  gemm_bt<bf16><<<dim3(4, 32,2), 256, 0, stream>>>(xb, Wkb, Wvb, kbuf, vraw, NKV_*HD_, H_);
  postproc<<<dim3(M_), 256, 0, stream>>>(qbuf, kbuf, qw, kw);
  vtrans<<<dim3(T_/64, (NKV_*HD_)/64, B_), 256, 0, stream>>>(vraw, Vt);
  attn<<<dim3(64, NKV_, B_), 512, 0, stream>>>(qbuf, kbuf, Vt, att);
  gemm_bt<float><<<dim3(16,32,1), 256, 0, stream>>>(att, Wob, Wob, out, out, H_, NH_*HD_);
}

// Round 11
// 253.627 us; speedup vs baseline: 1.2780x; 1.2780x over previous
//
#include <hip/hip_runtime.h>
#include <hip/hip_bf16.h>
#include <stdint.h>

#define B_   2
#define T_   2048
#define H_   2048
#define NH_  16
#define NKV_ 4
#define HD_  128
#define M_   (B_*T_)
#define SCALE_ 0.08838834764831845f

typedef __hip_bfloat16 bf16;
typedef __attribute__((ext_vector_type(8))) short bh8;
typedef __attribute__((ext_vector_type(4))) float f32x4;
typedef __attribute__((ext_vector_type(4))) unsigned short us4;

__device__ __forceinline__ void gload16(const bf16* g, bf16* l) {
  __builtin_amdgcn_global_load_lds(
      (const __attribute__((address_space(1))) void*)g,
      (__attribute__((address_space(3))) void*)l, 16, 0, 0);
}

__device__ __forceinline__ void cstore(bf16* p, float v)  { *p = __float2bfloat16(v); }
__device__ __forceinline__ void cstore(float* p, float v) { *p = v; }

// fp32 -> bf16 elementwise (n multiple of 8)
__global__ __launch_bounds__(256) void cvt32to16(const float* __restrict__ src,
                                                 bf16* __restrict__ dst, int n)
{
  const int stride = gridDim.x * 256 * 8;
  for (int i = (blockIdx.x * 256 + threadIdx.x) * 8; i < n; i += stride) {
    const float4 a = *(const float4*)(src + i);
    const float4 b = *(const float4*)(src + i + 4);
    bf16 o[8];
    o[0]=__float2bfloat16(a.x); o[1]=__float2bfloat16(a.y);
    o[2]=__float2bfloat16(a.z); o[3]=__float2bfloat16(a.w);
    o[4]=__float2bfloat16(b.x); o[5]=__float2bfloat16(b.y);
    o[6]=__float2bfloat16(b.z); o[7]=__float2bfloat16(b.w);
    *(bh8*)(dst + i) = *(const bh8*)o;
  }
}

// C[m][n] = sum_k A[m][k] * Bmat[n][k];  A:[M][K] row-major, Bmat:[N][K] row-major.
template<typename OutT>
__global__ __launch_bounds__(256) void gemm_bt(
    const bf16* __restrict__ A,
    const bf16* __restrict__ B0, const bf16* __restrict__ B1,
    OutT* __restrict__ C0, OutT* __restrict__ C1,
    int N, int K)
{
  const bf16* Bm = (blockIdx.z == 0) ? B0 : B1;
  OutT* Cm       = (blockIdx.z == 0) ? C0 : C1;
  const int n0 = blockIdx.x * 128;
  const int m0 = blockIdx.y * 128;
  const int tid  = threadIdx.x;
  const int lane = tid & 63;
  const int w    = tid >> 6;
  const int wr   = w >> 1, wc = w & 1;
  const int l15  = lane & 15;
  const int lk   = (lane >> 4) * 8;
  const int srow = lane >> 3;
  const int scol = (lane & 7) * 8;

  __shared__ bf16 As[128*64];
  __shared__ bf16 Bs[128*64];

  f32x4 acc[4][4] = {};

  for (int k0 = 0; k0 < K; k0 += 64) {
    #pragma unroll
    for (int i = 0; i < 4; ++i) {
      const int chunk = w*4 + i;
      const int row   = chunk*8 + srow;
      gload16(A  + (size_t)(m0+row)*K + k0 + scol, &As[chunk*512 + lane*8]);
      gload16(Bm + (size_t)(n0+row)*K + k0 + scol, &Bs[chunk*512 + lane*8]);
    }
    __syncthreads();
    #pragma unroll
    for (int kk = 0; kk < 2; ++kk) {
      bh8 af[4], bfr[4];
      #pragma unroll
      for (int mi=0;mi<4;mi++) af[mi]  = *(const bh8*)&As[(wr*64 + mi*16 + l15)*64 + kk*32 + lk];
      #pragma unroll
      for (int nj=0;nj<4;nj++) bfr[nj] = *(const bh8*)&Bs[(wc*64 + nj*16 + l15)*64 + kk*32 + lk];
      #pragma unroll
      for (int mi=0;mi<4;mi++)
        #pragma unroll
        for (int nj=0;nj<4;nj++)
          acc[mi][nj] = __builtin_amdgcn_mfma_f32_16x16x32_bf16(af[mi], bfr[nj], acc[mi][nj], 0,0,0);
    }
    __syncthreads();
  }

  #pragma unroll
  for (int mi=0;mi<4;mi++)
    #pragma unroll
    for (int r=0;r<4;r++) {
      const int row = m0 + wr*64 + mi*16 + (lane>>4)*4 + r;
      #pragma unroll
      for (int nj=0;nj<4;nj++) {
        const int col = n0 + wc*64 + nj*16 + l15;
        cstore(&Cm[(size_t)row*N + col], acc[mi][nj][r]);
      }
    }
}

// Per (b,t): RMSNorm(HD) + RoPE IN PLACE. Lane l owns d=l and d=l+64.
__global__ __launch_bounds__(256) void postproc(
    bf16* __restrict__ q, bf16* __restrict__ k,
    const float* __restrict__ qw, const float* __restrict__ kw)
{
  const int blk  = blockIdx.x;
  const int t    = blk & (T_-1);
  const int lane = threadIdx.x & 63;
  const int w    = threadIdx.x >> 6;

  const float inv = expf(-(float)lane * (9.210340371976184f / 64.f));
  const float ang = (float)t * inv;
  const float cw = cosf(ang), sw = sinf(ang);

  #pragma unroll
  for (int hi = 0; hi < 4; ++hi) {
    const int h = w + hi*4;
    bf16* row = q + (size_t)blk*(NH_*HD_) + h*HD_;
    float x1 = __bfloat162float(row[lane]);
    float x2 = __bfloat162float(row[lane+64]);
    float ss = x1*x1 + x2*x2;
    #pragma unroll
    for (int m = 1; m < 64; m <<= 1) ss += __shfl_xor(ss, m, 64);
    const float rs = rsqrtf(ss*(1.f/128.f) + 1e-6f);
    const float n1 = x1*rs*(1.f + qw[lane]), n2 = x2*rs*(1.f + qw[lane+64]);
    row[lane]    = __float2bfloat16(n1*cw - n2*sw);
    row[lane+64] = __float2bfloat16(n2*cw + n1*sw);
  }
  {
    bf16* row = k + (size_t)blk*(NKV_*HD_) + w*HD_;
    float x1 = __bfloat162float(row[lane]);
    float x2 = __bfloat162float(row[lane+64]);
    float ss = x1*x1 + x2*x2;
    #pragma unroll
    for (int m = 1; m < 64; m <<= 1) ss += __shfl_xor(ss, m, 64);
    const float rs = rsqrtf(ss*(1.f/128.f) + 1e-6f);
    const float n1 = x1*rs*(1.f + kw[lane]), n2 = x2*rs*(1.f + kw[lane+64]);
    row[lane]    = __float2bfloat16(n1*cw - n2*sw);
    row[lane+64] = __float2bfloat16(n2*cw + n1*sw);
  }
}

// v_raw [b*T+t][kvh*128+d]  ->  Vt [b][kvh][d][T]
__global__ __launch_bounds__(256) void vtrans(const bf16* __restrict__ vraw,
                                              bf16* __restrict__ Vt)
{
  __shared__ bf16 tile[64][65];
  const int t0 = blockIdx.x * 64;
  const int c0 = blockIdx.y * 64;
  const int b  = blockIdx.z;
  const int tx = threadIdx.x & 63;
  const int ty = threadIdx.x >> 6;
  const bf16* src = vraw + (size_t)b * T_ * (NKV_*HD_);
  bf16* dst       = Vt   + (size_t)b * (NKV_*HD_) * T_;
  #pragma unroll
  for (int i = 0; i < 16; ++i) {
    const int r = i*4 + ty;
    tile[r][tx] = src[(size_t)(t0 + r)*(NKV_*HD_) + c0 + tx];
  }
  __syncthreads();
  #pragma unroll
  for (int i = 0; i < 16; ++i) {
    const int r = i*4 + ty;
    dst[(size_t)(c0 + r)*T_ + t0 + tx] = tile[tx][r];
  }
}

// Flash attention v7b: GQA-shared K/V, 8 waves = 4 heads x 2 q-halves per
// block. launch_bounds(512,4): VGPR cap 128 -> no spill (round-10 lesson:
// (512,6) forced VGPR=40 + 51MB scratch spill traffic). Balanced dispatch:
// logical (s,kvh,b) decoded from linear id so the first 256 dispatched
// blocks are the heavy slices -> each CU gets ~one heavy + one light block.
__global__ __launch_bounds__(512, 4) void attn(
    const bf16* __restrict__ Q, const bf16* __restrict__ Kb,
    const bf16* __restrict__ Vt, bf16* __restrict__ att)
{
  const int id  = blockIdx.x;          // 0..511
  const int s   = 63 - (id >> 3);      // 32-row q slice, heavy-first
  const int kvh = (id >> 1) & 3;       // 0..3
  const int b   = id & 1;              // 0..1
  const int tid = threadIdx.x, lane = tid & 63, w = tid >> 6;  // w 0..7
  const int h   = kvh*4 + (w & 3);     // this wave's q head
  const int l15 = lane & 15;
  const int g   = lane >> 4;           // 0..3
  const int lr4 = g * 4;
  const int swz = l15 & 7;             // read-side swizzle selector

  const int q0w = s*32 + (w >> 2)*16;  // this wave's 16 q-rows
  const int nt  = (s >> 1) + 1;        // KV tiles of 64

  __shared__ bf16 Ks[64*128];          // [kv][d], swizzled 16B slots
  __shared__ bf16 Vs[128*64];          // [d][kv], swizzled 16B slots
  __shared__ bf16 Plds[8][16*72];      // wave-private P

  const bf16* Kglob = Kb + (size_t)b*T_*(NKV_*HD_) + kvh*HD_;
  const bf16* Vglob = Vt + (size_t)(b*NKV_ + kvh)*HD_*T_;

  bh8 aQ[4];
  #pragma unroll
  for (int kk = 0; kk < 4; ++kk)
    aQ[kk] = *(const bh8*)&Q[(size_t)(b*T_ + q0w + l15)*(NH_*HD_) + h*HD_ + kk*32 + g*8];

  f32x4 acc[8] = {};
  float mL = -1e30f, lL = 0.f;

  for (int j = 0; j < nt; ++j) {
    const int kv0 = j*64;

    // stage K tile: 1024 x 16B chunks over 512 threads (2 each)
    #pragma unroll
    for (int i = 0; i < 2; ++i) {
      const int o = i*512 + tid;
      const int r = o >> 4, sl = o & 15;
      gload16(Kglob + (size_t)(kv0 + r)*(NKV_*HD_) + ((sl ^ (r & 7)) << 3),
              &Ks[o*8]);
    }
    // stage V tile
    #pragma unroll
    for (int i = 0; i < 2; ++i) {
      const int o = i*512 + tid;
      const int d = o >> 3, sl = o & 7;
      gload16(Vglob + (size_t)d*T_ + kv0 + ((sl ^ (d & 7)) << 3),
              &Vs[o*8]);
    }
    asm volatile("s_waitcnt vmcnt(0)" ::: "memory");
    __syncthreads();

    // QK^T (swapped): S[jb] rows = kv(jb*16+lr4+r), cols = q(l15)
    f32x4 S[4] = {};
    #pragma unroll
    for (int jb = 0; jb < 4; ++jb)
      #pragma unroll
      for (int kk = 0; kk < 4; ++kk) {
        const bh8 kf = *(const bh8*)&Ks[(jb*16 + l15)*128 + (((kk*4 + g) ^ swz) << 3)];
        S[jb] = __builtin_amdgcn_mfma_f32_16x16x32_bf16(kf, aQ[kk], S[jb], 0,0,0);
      }

    // in-lane online softmax: lane owns q-row = q0w + l15 (16 scores)
    const bool diag = (j == nt - 1);
    float sv[16];
    float mx = -1e30f;
    #pragma unroll
    for (int jb = 0; jb < 4; ++jb)
      #pragma unroll
      for (int r = 0; r < 4; ++r) {
        float sc = S[jb][r] * SCALE_;
        if (diag && (kv0 + jb*16 + lr4 + r) > (q0w + l15)) sc = -1e30f;
        sv[jb*4 + r] = sc;
        mx = fmaxf(mx, sc);
      }
    mx = fmaxf(mx, __shfl_xor(mx, 16, 64));
    mx = fmaxf(mx, __shfl_xor(mx, 32, 64));
    const float mn = fmaxf(mL, mx);
    const float al = __expf(mL - mn);
    mL = mn;
    float sum = 0.f;
    #pragma unroll
    for (int i = 0; i < 16; ++i) { sv[i] = __expf(sv[i] - mn); sum += sv[i]; }
    sum += __shfl_xor(sum, 16, 64);
    sum += __shfl_xor(sum, 32, 64);
    lL = lL*al + sum;

    // P -> wave-private LDS (row q = l15, col kv)
    bf16* pl = Plds[w];
    #pragma unroll
    for (int jb = 0; jb < 4; ++jb) {
      bf16 pk[4];
      #pragma unroll
      for (int r = 0; r < 4; ++r) pk[r] = __float2bfloat16(sv[jb*4 + r]);
      *(us4*)(&pl[l15*72 + jb*16 + lr4]) = *(const us4*)pk;
    }

    // rescale acc (rows q = q0w + lr4 + r): al from lane with l15 = lr4+r
    float alr[4];
    #pragma unroll
    for (int r = 0; r < 4; ++r)
      alr[r] = __shfl(al, (lane & 48) | (lr4 + r), 64);
    #pragma unroll
    for (int jd = 0; jd < 8; ++jd)
      #pragma unroll
      for (int r = 0; r < 4; ++r) acc[jd][r] *= alr[r];

    // wave-local ds_write -> ds_read ordering (rule 18)
    asm volatile("s_waitcnt lgkmcnt(0)" ::: "memory");
    __builtin_amdgcn_sched_barrier(0);

    const bh8 pa0 = *(const bh8*)&pl[l15*72 + g*8];
    const bh8 pa1 = *(const bh8*)&pl[l15*72 + 32 + g*8];
    #pragma unroll
    for (int jd = 0; jd < 8; ++jd) {
      const bh8 vf0 = *(const bh8*)&Vs[(jd*16 + l15)*64 + (((g    ) ^ swz) << 3)];
      const bh8 vf1 = *(const bh8*)&Vs[(jd*16 + l15)*64 + (((4 + g) ^ swz) << 3)];
      acc[jd] = __builtin_amdgcn_mfma_f32_16x16x32_bf16(pa0, vf0, acc[jd], 0,0,0);
      acc[jd] = __builtin_amdgcn_mfma_f32_16x16x32_bf16(pa1, vf1, acc[jd], 0,0,0);
    }
    __syncthreads();   // all waves done with Ks/Vs before next staging
  }

  // epilogue: bring 1/l into acc row-space and store
  float lar[4];
  #pragma unroll
  for (int r = 0; r < 4; ++r)
    lar[r] = __shfl(lL, (lane & 48) | (lr4 + r), 64);
  #pragma unroll
  for (int r = 0; r < 4; ++r) {
    const float inv = 1.f / lar[r];
    const int row = q0w + lr4 + r;
    bf16* orow = att + ((size_t)(b*T_ + row))*(NH_*HD_) + h*HD_;
    #pragma unroll
    for (int jd = 0; jd < 8; ++jd)
      orow[jd*16 + l15] = __float2bfloat16(acc[jd][r] * inv);
  }
}

extern "C" void kernel_launch(void* const* d_in, const int* in_sizes, int n_in,
                              void* d_out, int out_size, void* d_ws, size_t ws_size,
                              hipStream_t stream) {
  const float* x  = (const float*)d_in[0];
  const float* Wq = (const float*)d_in[1];
  const float* Wk = (const float*)d_in[2];
  const float* Wv = (const float*)d_in[3];
  const float* Wo = (const float*)d_in[4];
  const float* qw = (const float*)d_in[5];
  const float* kw = (const float*)d_in[6];
  float* out = (float*)d_out;

  char* ws = (char*)d_ws;
  bf16* xb   = (bf16*)(ws);                  // 16MB  (-> att later)
  bf16* Wqb  = (bf16*)(ws + (16u<<20));      // 8MB
  bf16* Wkb  = (bf16*)(ws + (24u<<20));      // 2MB
  bf16* Wvb  = (bf16*)(ws + (26u<<20));      // 2MB
  bf16* Wob  = (bf16*)(ws + (28u<<20));      // 8MB
  bf16* kbuf = (bf16*)(ws + (36u<<20));      // 4MB
  bf16* vraw = (bf16*)(ws + (40u<<20));      // 4MB
  bf16* Vt   = (bf16*)(ws + (44u<<20));      // 4MB
  bf16* att  = xb;
  bf16* qbuf = (bf16*)d_out;                 // Q scratch in d_out

  cvt32to16<<<dim3(2048), 256, 0, stream>>>(x,  xb,  M_*H_);
  cvt32to16<<<dim3(1024), 256, 0, stream>>>(Wq, Wqb, NH_*HD_*H_);
  cvt32to16<<<dim3(256),  256, 0, stream>>>(Wk, Wkb, NKV_*HD_*H_);
  cvt32to16<<<dim3(256),  256, 0, stream>>>(Wv, Wvb, NKV_*HD_*H_);
  cvt32to16<<<dim3(1024), 256, 0, stream>>>(Wo, Wob, H_*NH_*HD_);

  gemm_bt<bf16><<<dim3(16,32,1), 256, 0, stream>>>(xb, Wqb, Wqb, qbuf, qbuf, NH_*HD_, H_);
  gemm_bt<bf16><<<dim3(4, 32,2), 256, 0, stream>>>(xb, Wkb, Wvb, kbuf, vraw, NKV_*HD_, H_);
  postproc<<<dim3(M_), 256, 0, stream>>>(qbuf, kbuf, qw, kw);
  vtrans<<<dim3(T_/64, (NKV_*HD_)/64, B_), 256, 0, stream>>>(vraw, Vt);
  attn<<<dim3(512, 1, 1), 512, 0, stream>>>(qbuf, kbuf, Vt, att);
  gemm_bt<float><<<dim3(16,32,1), 256, 0, stream>>>(att, Wob, Wob, out, out, H_, NH_*HD_);
}